// Round 6
// baseline (893.168 us; speedup 1.0000x reference)
//
#include <hip/hip_runtime.h>

#define B_  64
#define T_  256
#define H_  512
#define NH_ 8
#define DH_ 64
#define M_  16384
#define SL  262144  // 512*512 elements per weight slot

typedef float  f32x4 __attribute__((ext_vector_type(4)));
typedef __bf16 b16x8 __attribute__((ext_vector_type(8)));
typedef __bf16 b16x4 __attribute__((ext_vector_type(4)));
typedef __bf16 b16x2 __attribute__((ext_vector_type(2)));

__device__ __forceinline__ void gload16(const void* g, void* l) {
  __builtin_amdgcn_global_load_lds((const __attribute__((address_space(1))) void*)g,
                                   (__attribute__((address_space(3))) void*)l, 16, 0, 0);
}

// ---------------- fp32 -> bf16 convert ----------------
__global__ __launch_bounds__(256) void cvt_f32_bf16_k(const float* __restrict__ in,
                                                      __bf16* __restrict__ out) {
  size_t i = ((size_t)blockIdx.x * 256 + threadIdx.x) * 4;
  f32x4 v = *(const f32x4*)(in + i);
  b16x4 o;
  o[0] = (__bf16)v[0]; o[1] = (__bf16)v[1]; o[2] = (__bf16)v[2]; o[3] = (__bf16)v[3];
  *(b16x4*)(out + i) = o;
}

// ---------------- batched weight transpose: up to 15 (512x512) slices ----------------
struct TP15 { const float* src[15]; int slot[15]; };
__global__ __launch_bounds__(256) void transpose_cvt15(TP15 p, __bf16* __restrict__ wT) {
  __shared__ float tile[32][33];
  const float* in = p.src[blockIdx.z];
  __bf16* out = wT + (size_t)p.slot[blockIdx.z] * SL;
  int c0 = blockIdx.x * 32, r0 = blockIdx.y * 32;
  int tx = threadIdx.x & 31, ty = threadIdx.x >> 5;
  for (int yy = ty; yy < 32; yy += 8)
    tile[yy][tx] = in[(size_t)(r0 + yy) * 512 + c0 + tx];
  __syncthreads();
  for (int yy = ty; yy < 32; yy += 8)
    out[(size_t)(c0 + yy) * 512 + r0 + tx] = (__bf16)tile[tx][yy];
}

// ---------------- generic transpose + convert (for W1: 2048x512) ----------------
__global__ __launch_bounds__(256) void transpose_cvt(const float* __restrict__ in,
                                                     __bf16* __restrict__ out, int R, int C) {
  __shared__ float tile[32][33];
  int c0 = blockIdx.x * 32, r0 = blockIdx.y * 32;
  int tx = threadIdx.x & 31, ty = threadIdx.x >> 5;
  for (int yy = ty; yy < 32; yy += 8)
    tile[yy][tx] = in[(size_t)(r0 + yy) * C + c0 + tx];
  __syncthreads();
  for (int yy = ty; yy < 32; yy += 8)
    out[(size_t)(c0 + yy) * R + r0 + tx] = (__bf16)tile[tx][yy];
}

// ---------------- emotion K/V: (7,512) = emo @ W + b ----------------
__global__ __launch_bounds__(512) void emo_kv(const float* __restrict__ emo,
                                              const float* __restrict__ Wk, const float* __restrict__ bk,
                                              const float* __restrict__ Wv, const float* __restrict__ bv,
                                              float* __restrict__ kout, float* __restrict__ vout) {
  int e = blockIdx.x, n = threadIdx.x;
  const float* W = blockIdx.y ? Wv : Wk;
  const float* bb = blockIdx.y ? bv : bk;
  float* o = blockIdx.y ? vout : kout;
  float acc = 0.f;
  for (int kk = 0; kk < 512; ++kk) acc += emo[e * 512 + kk] * W[kk * 512 + n];
  o[e * 512 + n] = acc + bb[n];
}

// ---------------- sentiment precompute: Wqk[he][r], VWo[he][o], sbias[he] ----------------
__global__ __launch_bounds__(512) void sentprep(const float* __restrict__ Wq,
                                                const float* __restrict__ bq,
                                                const float* __restrict__ Wo,
                                                const float* __restrict__ kemo,
                                                const float* __restrict__ vemo,
                                                float* __restrict__ Wqk,
                                                float* __restrict__ VWo,
                                                float* __restrict__ sbias) {
  const int he = blockIdx.x, h = he / 7, e = he % 7;
  const int t = threadIdx.x;
  const float* kp = kemo + e * 512 + h * 64;
  const float* wqr = Wq + (size_t)t * 512 + h * 64;
  float a = 0.f;
#pragma unroll 8
  for (int d = 0; d < 64; ++d) a += wqr[d] * kp[d];
  Wqk[he * 512 + t] = a;
  const float* vp = vemo + e * 512 + h * 64;
  float v = 0.f;
#pragma unroll 8
  for (int d = 0; d < 64; ++d) v += vp[d] * Wo[(size_t)(h * 64 + d) * 512 + t];
  VWo[he * 512 + t] = v;
  if (t == 0) {
    float s = 0.f;
    for (int d = 0; d < 64; ++d) s += bq[h * 64 + d] * kp[d];
    sbias[he] = s;
  }
}

// ---------------- bias helpers ----------------
__global__ __launch_bounds__(512) void concat_qk_bias(const float* __restrict__ bq,
                                                      const float* __restrict__ bk,
                                                      float* __restrict__ out) {
  int i = blockIdx.x, t = threadIdx.x;
  out[i * 1024 + t]       = bq[i * 512 + t];
  out[i * 1024 + 512 + t] = bk[i * 512 + t];
}

__global__ __launch_bounds__(256) void bias2_p1(const float* __restrict__ bo,
                                                const float* __restrict__ W1,
                                                float* __restrict__ partial) {
  int p = blockIdx.x, t = threadIdx.x;
  float a0 = 0.f, a1 = 0.f;
  for (int g = p * 128; g < p * 128 + 128; ++g) {
    float bg = bo[g];
    a0 += bg * W1[(size_t)g * 512 + t];
    a1 += bg * W1[(size_t)g * 512 + 256 + t];
  }
  partial[p * 512 + t] = a0;
  partial[p * 512 + 256 + t] = a1;
}

__global__ __launch_bounds__(256) void bias2_p2(const float* __restrict__ b1,
                                                const float* __restrict__ partial,
                                                float* __restrict__ out) {
  int o = blockIdx.x * 256 + threadIdx.x;
  float acc = b1[o];
#pragma unroll
  for (int p = 0; p < 16; ++p) acc += partial[p * 512 + o];
  out[o] = acc;
}

// ---------------- MFMA GEMM 128x128 (m97 structure + XCD swizzle) ----------------
template<bool OB, int BM>
__global__ __launch_bounds__(256) void gemm_bt(const __bf16* __restrict__ A,
                                               const __bf16* __restrict__ Bt,
                                               const float* __restrict__ bias,
                                               void* __restrict__ Cv,
                                               int N, int K, int lda, int ldc,
                                               size_t zA, size_t zB, size_t zC) {
  __shared__ __attribute__((aligned(16))) __bf16 As[128 * 32];
  __shared__ __attribute__((aligned(16))) __bf16 Bs[128 * 32];
  A  += (size_t)blockIdx.z * zA;
  Bt += (size_t)blockIdx.z * zB;
  char* Cb = (char*)Cv + (size_t)blockIdx.z * zC * (OB ? 2 : 4);
  const int gx = gridDim.x;
  const int nwg = gx * gridDim.y;
  const int bid = blockIdx.y * gx + blockIdx.x;
  const int cpx = nwg >> 3;
  const int swz = (bid & 7) * cpx + (bid >> 3);
  const int bx = swz % gx, by = swz / gx;
  const int tid = threadIdx.x, lane = tid & 63, wid = tid >> 6;
  const int wm = wid & 1, wn = wid >> 1;
  const int m0 = by * 128, n0 = bx * 128;
  const int l15 = lane & 15, l16 = lane >> 4;
  const int r0 = tid >> 2, o0 = (tid & 3) * 8;
  const __bf16* a0 = A + (size_t)(m0 + r0) * lda + o0;
  const __bf16* a1 = A + (size_t)(m0 + 64 + r0) * lda + o0;
  const __bf16* bp0 = Bt + (size_t)(n0 + r0) * K + o0;
  const __bf16* bp1 = Bt + (size_t)(n0 + 64 + r0) * K + o0;
  char* AsW = (char*)As + wid * 1024;
  char* BsW = (char*)Bs + wid * 1024;
  f32x4 acc[4][4] = {};
  for (int k0 = 0; k0 < K; k0 += 32) {
    gload16(a0 + k0, AsW);
    gload16(a1 + k0, AsW + 4096);
    gload16(bp0 + k0, BsW);
    gload16(bp1 + k0, BsW + 4096);
    __syncthreads();
    b16x8 af[4], bf[4];
#pragma unroll
    for (int m = 0; m < 4; ++m) af[m] = *(const b16x8*)&As[(wm * 64 + m * 16 + l15) * 32 + l16 * 8];
#pragma unroll
    for (int n = 0; n < 4; ++n) bf[n] = *(const b16x8*)&Bs[(wn * 64 + n * 16 + l15) * 32 + l16 * 8];
#pragma unroll
    for (int m = 0; m < 4; ++m)
#pragma unroll
      for (int n = 0; n < 4; ++n)
        acc[m][n] = __builtin_amdgcn_mfma_f32_16x16x32_bf16(af[m], bf[n], acc[m][n], 0, 0, 0);
    __syncthreads();
  }
  const int rbase = m0 + wm * 64 + l16 * 4;
  const int cb = n0 + wn * 64 + l15;
#pragma unroll
  for (int n = 0; n < 4; ++n) {
    int gc = cb + n * 16;
    float bc = (BM == 1) ? bias[gc] : 0.0f;
#pragma unroll
    for (int m = 0; m < 4; ++m) {
#pragma unroll
      for (int rr = 0; rr < 4; ++rr) {
        int gr = rbase + m * 16 + rr;
        float val = acc[m][n][rr] + ((BM == 2) ? bias[gr] : bc);
        if (OB) ((__bf16*)Cb)[(size_t)gr * ldc + gc] = (__bf16)val;
        else    ((float*)Cb)[(size_t)gr * ldc + gc] = val;
      }
    }
  }
}

// ---------------- MFMA GEMM 128x64 (higher occupancy for skinny N) ----------------
template<bool OB, int BM>
__global__ __launch_bounds__(256) void gemm_bt64(const __bf16* __restrict__ A,
                                                 const __bf16* __restrict__ Bt,
                                                 const float* __restrict__ bias,
                                                 void* __restrict__ Cv,
                                                 int N, int K, int lda, int ldc,
                                                 size_t zA, size_t zB, size_t zC) {
  __shared__ __attribute__((aligned(16))) __bf16 As[128 * 32];
  __shared__ __attribute__((aligned(16))) __bf16 Bs[64 * 32];
  A  += (size_t)blockIdx.z * zA;
  Bt += (size_t)blockIdx.z * zB;
  char* Cb = (char*)Cv + (size_t)blockIdx.z * zC * (OB ? 2 : 4);
  const int gx = gridDim.x;
  const int nwg = gx * gridDim.y;
  const int bid = blockIdx.y * gx + blockIdx.x;
  const int cpx = nwg >> 3;
  const int swz = (bid & 7) * cpx + (bid >> 3);
  const int bx = swz % gx, by = swz / gx;
  const int tid = threadIdx.x, lane = tid & 63, wid = tid >> 6;
  const int m0 = by * 128, n0 = bx * 64;
  const int l15 = lane & 15, l16 = lane >> 4;
  const int r0 = tid >> 2, o0 = (tid & 3) * 8;
  const __bf16* a0 = A + (size_t)(m0 + r0) * lda + o0;
  const __bf16* a1 = A + (size_t)(m0 + 64 + r0) * lda + o0;
  const __bf16* bp0 = Bt + (size_t)(n0 + r0) * K + o0;
  char* AsW = (char*)As + wid * 1024;
  char* BsW = (char*)Bs + wid * 1024;
  f32x4 acc[2][4] = {};
  for (int k0 = 0; k0 < K; k0 += 32) {
    gload16(a0 + k0, AsW);
    gload16(a1 + k0, AsW + 4096);
    gload16(bp0 + k0, BsW);
    __syncthreads();
    b16x8 af[2], bf[4];
#pragma unroll
    for (int m = 0; m < 2; ++m) af[m] = *(const b16x8*)&As[(wid * 32 + m * 16 + l15) * 32 + l16 * 8];
#pragma unroll
    for (int n = 0; n < 4; ++n) bf[n] = *(const b16x8*)&Bs[(n * 16 + l15) * 32 + l16 * 8];
#pragma unroll
    for (int m = 0; m < 2; ++m)
#pragma unroll
      for (int n = 0; n < 4; ++n)
        acc[m][n] = __builtin_amdgcn_mfma_f32_16x16x32_bf16(af[m], bf[n], acc[m][n], 0, 0, 0);
    __syncthreads();
  }
  const int rbase = m0 + wid * 32 + l16 * 4;
  const int cb = n0 + l15;
#pragma unroll
  for (int n = 0; n < 4; ++n) {
    int gc = cb + n * 16;
    float bc = (BM == 1) ? bias[gc] : 0.0f;
#pragma unroll
    for (int m = 0; m < 2; ++m) {
#pragma unroll
      for (int rr = 0; rr < 4; ++rr) {
        int gr = rbase + m * 16 + rr;
        float val = acc[m][n][rr] + ((BM == 2) ? bias[gr] : bc);
        if (OB) ((__bf16*)Cb)[(size_t)gr * ldc + gc] = (__bf16)val;
        else    ((float*)Cb)[(size_t)gr * ldc + gc] = val;
      }
    }
  }
}

// ---------------- fused sentiment block: scores -> softmax -> P@VWo + bo + x -> LN ----------------
// 8 lanes per token; lane ch owns dims {h2*64 + ch*8 + j}
__global__ __launch_bounds__(256) void sent_fused(const __bf16* __restrict__ xb,
                                                  const float* __restrict__ x,
                                                  const float* __restrict__ Wqk,
                                                  const float* __restrict__ VWo,
                                                  const float* __restrict__ sbias,
                                                  const float* __restrict__ bo,
                                                  const float* __restrict__ g,
                                                  const float* __restrict__ bt,
                                                  __bf16* __restrict__ htb) {
  const int lane = threadIdx.x & 63;
  const int tok = blockIdx.x * 32 + (threadIdx.x >> 6) * 8 + (lane >> 3);
  const int ch = lane & 7;
  const size_t rowb = (size_t)tok * 512;
  float xf[64], pre[64];
#pragma unroll
  for (int h2 = 0; h2 < 8; ++h2) {
    const int off = h2 * 64 + ch * 8;
    b16x8 xq = *(const b16x8*)(xb + rowb + off);
    f32x4 r0 = *(const f32x4*)(x + rowb + off);
    f32x4 r1 = *(const f32x4*)(x + rowb + off + 4);
    f32x4 b0 = *(const f32x4*)(bo + off);
    f32x4 b1 = *(const f32x4*)(bo + off + 4);
#pragma unroll
    for (int j = 0; j < 4; ++j) {
      xf[h2 * 8 + j]     = (float)xq[j];
      xf[h2 * 8 + 4 + j] = (float)xq[4 + j];
      pre[h2 * 8 + j]     = r0[j] + b0[j];
      pre[h2 * 8 + 4 + j] = r1[j] + b1[j];
    }
  }
#pragma unroll
  for (int h = 0; h < 8; ++h) {
    float ev[7];
    float mx = -3.4e38f;
#pragma unroll
    for (int e = 0; e < 7; ++e) {
      const int he = h * 7 + e;
      const float* wr = Wqk + he * 512 + ch * 8;
      float pr = 0.f;
#pragma unroll
      for (int h2 = 0; h2 < 8; ++h2) {
        f32x4 w0 = *(const f32x4*)(wr + h2 * 64);
        f32x4 w1 = *(const f32x4*)(wr + h2 * 64 + 4);
#pragma unroll
        for (int j = 0; j < 4; ++j)
          pr += xf[h2 * 8 + j] * w0[j] + xf[h2 * 8 + 4 + j] * w1[j];
      }
      pr += __shfl_xor(pr, 1); pr += __shfl_xor(pr, 2); pr += __shfl_xor(pr, 4);
      float s = (pr + sbias[he]) * 0.125f;
      ev[e] = s; mx = fmaxf(mx, s);
    }
    float sum = 0.f;
#pragma unroll
    for (int e = 0; e < 7; ++e) { ev[e] = __expf(ev[e] - mx); sum += ev[e]; }
    float inv = 1.f / sum;
#pragma unroll
    for (int e = 0; e < 7; ++e) {
      const int he = h * 7 + e;
      const float p = ev[e] * inv;
      const float* vr = VWo + he * 512 + ch * 8;
#pragma unroll
      for (int h2 = 0; h2 < 8; ++h2) {
        f32x4 v0 = *(const f32x4*)(vr + h2 * 64);
        f32x4 v1 = *(const f32x4*)(vr + h2 * 64 + 4);
#pragma unroll
        for (int j = 0; j < 4; ++j) {
          pre[h2 * 8 + j]     += p * v0[j];
          pre[h2 * 8 + 4 + j] += p * v1[j];
        }
      }
    }
  }
  // LayerNorm across the 8-lane group (512 dims)
  float sm = 0.f, sq = 0.f;
#pragma unroll
  for (int i = 0; i < 64; ++i) { sm += pre[i]; sq += pre[i] * pre[i]; }
  sm += __shfl_xor(sm, 1); sm += __shfl_xor(sm, 2); sm += __shfl_xor(sm, 4);
  sq += __shfl_xor(sq, 1); sq += __shfl_xor(sq, 2); sq += __shfl_xor(sq, 4);
  float mean = sm * (1.f / 512.f);
  float var = sq * (1.f / 512.f) - mean * mean;
  float rstd = rsqrtf(fmaxf(var, 0.f) + 1e-12f);
#pragma unroll
  for (int h2 = 0; h2 < 8; ++h2) {
    const int off = h2 * 64 + ch * 8;
    f32x4 g0 = *(const f32x4*)(g + off);
    f32x4 g1 = *(const f32x4*)(g + off + 4);
    f32x4 t0 = *(const f32x4*)(bt + off);
    f32x4 t1 = *(const f32x4*)(bt + off + 4);
    b16x8 o;
#pragma unroll
    for (int j = 0; j < 4; ++j) {
      o[j]     = (__bf16)((pre[h2 * 8 + j]     - mean) * rstd * g0[j] + t0[j]);
      o[4 + j] = (__bf16)((pre[h2 * 8 + 4 + j] - mean) * rstd * g1[j] + t1[j]);
    }
    *(b16x8*)(htb + rowb + off) = o;
  }
}

// ---------------- bf16+bf16 residual LayerNorm ----------------
__global__ __launch_bounds__(256) void ln2_bb(const __bf16* __restrict__ pre,
                                              const __bf16* __restrict__ res,
                                              const float* __restrict__ g,
                                              const float* __restrict__ bt,
                                              __bf16* __restrict__ ob) {
  int row = blockIdx.x, t = threadIdx.x;
  size_t base = (size_t)row * 512;
  b16x2 p2 = *(const b16x2*)(pre + base + 2 * t);
  b16x2 r2 = *(const b16x2*)(res + base + 2 * t);
  float v0 = (float)p2[0] + (float)r2[0];
  float v1 = (float)p2[1] + (float)r2[1];
  float s = v0 + v1, q = v0 * v0 + v1 * v1;
#pragma unroll
  for (int off = 32; off; off >>= 1) { s += __shfl_xor(s, off); q += __shfl_xor(q, off); }
  __shared__ float ls[4], lq[4];
  int wid = t >> 6, lane = t & 63;
  if (lane == 0) { ls[wid] = s; lq[wid] = q; }
  __syncthreads();
  s = ls[0] + ls[1] + ls[2] + ls[3];
  q = lq[0] + lq[1] + lq[2] + lq[3];
  float mean = s * (1.f / 512.f);
  float var = q * (1.f / 512.f) - mean * mean;
  float rstd = rsqrtf(fmaxf(var, 0.f) + 1e-12f);
  b16x2 o;
  o[0] = (__bf16)((v0 - mean) * rstd * g[2 * t] + bt[2 * t]);
  o[1] = (__bf16)((v1 - mean) * rstd * g[2 * t + 1] + bt[2 * t + 1]);
  *(b16x2*)(ob + base + 2 * t) = o;
}

// ---------------- fused masked attention; P overlays Ks; V prefetch ----------------
template<int BR>
__global__ __launch_bounds__(256, 4) void attn_branch(const __bf16* __restrict__ q,
                                                      const __bf16* __restrict__ kk_,
                                                      const __bf16* __restrict__ vt,
                                                      __bf16* __restrict__ ctx,
                                                      const int* __restrict__ lengths,
                                                      const int* __restrict__ speakers,
                                                      int sqk, int so) {
  __shared__ __attribute__((aligned(16))) __bf16 Ks[256 * 64];
  __shared__ float redM[2][32];
  __shared__ float redS[2][32];
  __shared__ float rowinv[32];
  __shared__ int spk[256];
  const int tid = threadIdx.x, lane = tid & 63, wid = tid >> 6;
  const int l15 = lane & 15, l16 = lane >> 4;
  const int bh = blockIdx.x, q0 = blockIdx.y * 32;
  const int b = bh >> 3, h = bh & 7;
  const int wq = wid & 1, wk = wid >> 1;
  const int mh = wid & 1, nh = wid >> 1;
  const __bf16* vb2 = vt + (size_t)(h * DH_) * M_ + b * T_;

  {
    const size_t kb0 = (size_t)(b * T_) * sqk + h * DH_;
    const int rsub = lane >> 3, slot = lane & 7;
#pragma unroll
    for (int j = 0; j < 8; ++j) {
      int row = (j * 4 + wid) * 8 + rsub;
      gload16(kk_ + kb0 + (size_t)row * sqk + ((slot ^ (row & 7)) * 8),
              (char*)Ks + (j * 4 + wid) * 1024);
    }
  }
  spk[tid] = speakers[b * T_ + tid];
  b16x8 af0, af1;
  {
    const __bf16* qr = q + (size_t)(b * T_ + q0 + wq * 16 + l15) * sqk + h * DH_;
    af0 = *(const b16x8*)(qr + l16 * 8);
    af1 = *(const b16x8*)(qr + 32 + l16 * 8);
  }
  __syncthreads();

  f32x4 sa[4][2] = {};
#pragma unroll
  for (int kc = 0; kc < 4; ++kc) {
#pragma unroll
    for (int nn = 0; nn < 2; ++nn) {
      int krw = kc * 64 + wk * 32 + nn * 16 + l15;
      b16x8 b0 = *(const b16x8*)((char*)Ks + krw * 128 + ((l16 ^ (krw & 7)) * 16));
      sa[kc][nn] = __builtin_amdgcn_mfma_f32_16x16x32_bf16(af0, b0, sa[kc][nn], 0, 0, 0);
      b16x8 b1 = *(const b16x8*)((char*)Ks + krw * 128 + (((4 + l16) ^ (krw & 7)) * 16));
      sa[kc][nn] = __builtin_amdgcn_mfma_f32_16x16x32_bf16(af1, b1, sa[kc][nn], 0, 0, 0);
    }
  }

  b16x8 vpre[2][2];
#pragma unroll
  for (int kt = 0; kt < 2; ++kt)
#pragma unroll
    for (int n = 0; n < 2; ++n) {
      int d = nh * 32 + n * 16 + l15;
      vpre[kt][n] = *(const b16x8*)(vb2 + (size_t)d * M_ + kt * 32 + l16 * 8);
    }

  const int L = lengths[b];
  const int rloc = wq * 16 + l16 * 4;
  float ev[4][8];
  float mx[4];
#pragma unroll
  for (int rr = 0; rr < 4; ++rr) {
    const int j = q0 + rloc + rr;
    const int spj = spk[j];
    const bool rv = j < L;
    mx[rr] = -3.4e38f;
#pragma unroll
    for (int kc = 0; kc < 4; ++kc)
#pragma unroll
      for (int nn = 0; nn < 2; ++nn) {
        int c = kc * 64 + wk * 32 + nn * 16 + l15;
        int dj = j - c;
        bool ok;
        if (BR == 0)      ok = (c < L);
        else if (BR == 1) ok = rv && (c < L) && (dj <= 2) && (dj >= -2);
        else if (BR == 2) ok = rv && (spk[c] == spj);
        else              ok = rv && (spk[c] != spj) && (c < L);
        float s = sa[kc][nn][rr] * 0.125f + (ok ? 0.0f : -10000.0f);
        ev[rr][kc * 2 + nn] = s;
        mx[rr] = fmaxf(mx[rr], s);
      }
    mx[rr] = fmaxf(mx[rr], __shfl_xor(mx[rr], 1));
    mx[rr] = fmaxf(mx[rr], __shfl_xor(mx[rr], 2));
    mx[rr] = fmaxf(mx[rr], __shfl_xor(mx[rr], 4));
    mx[rr] = fmaxf(mx[rr], __shfl_xor(mx[rr], 8));
  }
  if (l15 == 0) {
#pragma unroll
    for (int rr = 0; rr < 4; ++rr) redM[wk][rloc + rr] = mx[rr];
  }
  __syncthreads();
  float sm[4];
#pragma unroll
  for (int rr = 0; rr < 4; ++rr) {
    float mxf = fmaxf(redM[0][rloc + rr], redM[1][rloc + rr]);
    float s = 0.f;
#pragma unroll
    for (int i = 0; i < 8; ++i) { float e = __expf(ev[rr][i] - mxf); ev[rr][i] = e; s += e; }
    s += __shfl_xor(s, 1); s += __shfl_xor(s, 2); s += __shfl_xor(s, 4); s += __shfl_xor(s, 8);
    sm[rr] = s;
  }
  if (l15 == 0) {
#pragma unroll
    for (int rr = 0; rr < 4; ++rr) redS[wk][rloc + rr] = sm[rr];
  }
  __syncthreads();
  __bf16* P = (__bf16*)Ks;
#pragma unroll
  for (int rr = 0; rr < 4; ++rr) {
    if (wk == 0 && l15 == 0)
      rowinv[rloc + rr] = 1.0f / (redS[0][rloc + rr] + redS[1][rloc + rr]);
#pragma unroll
    for (int kc = 0; kc < 4; ++kc)
#pragma unroll
      for (int nn = 0; nn < 2; ++nn)
        P[(rloc + rr) * 260 + kc * 64 + wk * 32 + nn * 16 + l15] = (__bf16)ev[rr][kc * 2 + nn];
  }
  __syncthreads();

  f32x4 oa[2] = {};
#pragma unroll
  for (int kt = 0; kt < 8; ++kt) {
    b16x8 afp = *(const b16x8*)(P + (mh * 16 + l15) * 260 + kt * 32 + l16 * 8);
#pragma unroll
    for (int n = 0; n < 2; ++n) {
      b16x8 bfr;
      if (kt < 2) bfr = vpre[kt][n];
      else {
        int d = nh * 32 + n * 16 + l15;
        bfr = *(const b16x8*)(vb2 + (size_t)d * M_ + kt * 32 + l16 * 8);
      }
      oa[n] = __builtin_amdgcn_mfma_f32_16x16x32_bf16(afp, bfr, oa[n], 0, 0, 0);
    }
  }
#pragma unroll
  for (int n = 0; n < 2; ++n)
#pragma unroll
    for (int rr = 0; rr < 4; ++rr) {
      int row = mh * 16 + l16 * 4 + rr;
      ctx[(size_t)(b * T_ + q0 + row) * so + h * DH_ + nh * 32 + n * 16 + l15]
          = (__bf16)(oa[n][rr] * rowinv[row]);
    }
}

// ============================================================================
extern "C" void kernel_launch(void* const* d_in, const int* in_sizes, int n_in,
                              void* d_out, int out_size, void* d_ws, size_t ws_size,
                              hipStream_t stream) {
  const float* x        = (const float*)d_in[0];
  const int*   lengths  = (const int*)d_in[1];
  const int*   speakers = (const int*)d_in[2];
  const float* emo      = (const float*)d_in[3];
  const float* t_Wq = (const float*)d_in[4];
  const float* t_bq = (const float*)d_in[5];
  const float* t_Wk = (const float*)d_in[6];
  const float* t_bk = (const float*)d_in[7];
  const float* t_Wv = (const float*)d_in[8];
  const float* t_bv = (const float*)d_in[9];
  const float* t_Wo = (const float*)d_in[10];
  const float* t_bo = (const float*)d_in[11];
  const float* t_ln_g = (const float*)d_in[12];
  const float* t_ln_b = (const float*)d_in[13];
  const float* b_Wq = (const float*)d_in[14];
  const float* b_bq = (const float*)d_in[15];
  const float* b_Wk = (const float*)d_in[16];
  const float* b_bk = (const float*)d_in[17];
  const float* b_Wv = (const float*)d_in[18];
  const float* b_bv = (const float*)d_in[19];
  const float* b_Wo = (const float*)d_in[20];
  const float* b_bo = (const float*)d_in[21];
  const float* W1   = (const float*)d_in[22];
  const float* b1   = (const float*)d_in[23];
  const float* ln2_g = (const float*)d_in[24];
  const float* ln2_b = (const float*)d_in[25];
  const float* W2   = (const float*)d_in[26];

  if (ws_size < 232314880) return;

  char* ws = (char*)d_ws;
  // wT slots: 0=W2t  [2+2i,3+2i]=WqT_i/WkT_i  [10+i]=WvT_i  14..17=W1t
  __bf16* wT      = (__bf16*)(ws);              // 18 slots = 9,437,184 B
  __bf16* bWo_bf  = (__bf16*)(ws + 9437184);
  __bf16* Btbig   = (__bf16*)(ws + 11534336);
  float*  qkbias  = (float*)(ws + 13631488);
  float*  bias2   = (float*)(ws + 13647872);
  float*  kemo    = (float*)(ws + 13649920);
  float*  vemo    = (float*)(ws + 13664256);
  float*  Wqk     = (float*)(ws + 13678592);
  float*  VWo     = (float*)(ws + 13793280);
  float*  sbias   = (float*)(ws + 13907968);
  __bf16* xb      = (__bf16*)(ws + 13908224);   // reused as heb after sent_fused
  __bf16* htb     = (__bf16*)(ws + 30685440);
  __bf16* qkb     = (__bf16*)(ws + 47462656);   // per-branch [16384][1024]; tmpb + bias2 partial overlay
  __bf16* vtb_all = (__bf16*)(ws + 81017088);   // [2048][16384]
  __bf16* ctxa    = (__bf16*)(ws + 148125952);  // [16384][2048]
  __bf16* heb  = xb;
  __bf16* tmpb = qkb;           // dead qkb region after attn3
  float*  partial = (float*)qkb; // bias2 scratch, dead before first qk proj

  // conversions + transposes
  cvt_f32_bf16_k<<<dim3(8192), 256, 0, stream>>>(x, xb);
  cvt_f32_bf16_k<<<dim3(1024), 256, 0, stream>>>(b_Wo, bWo_bf);
  {
    TP15 p;
    const float* srcs[13] = {b_Wq, b_Wq + SL, b_Wq + 2 * SL, b_Wq + 3 * SL,
                             b_Wk, b_Wk + SL, b_Wk + 2 * SL, b_Wk + 3 * SL,
                             b_Wv, b_Wv + SL, b_Wv + 2 * SL, b_Wv + 3 * SL,
                             W2};
    const int slots[13] = {2, 4, 6, 8, 3, 5, 7, 9, 10, 11, 12, 13, 0};
    for (int i = 0; i < 13; ++i) { p.src[i] = srcs[i]; p.slot[i] = slots[i]; }
    for (int i = 13; i < 15; ++i) { p.src[i] = W2; p.slot[i] = 1; }
    transpose_cvt15<<<dim3(16, 16, 13), 256, 0, stream>>>(p, wT);
  }
  transpose_cvt<<<dim3(16, 64), 256, 0, stream>>>(W1, wT + 14 * SL, 2048, 512);
  emo_kv<<<dim3(7, 2), 512, 0, stream>>>(emo, t_Wk, t_bk, t_Wv, t_bv, kemo, vemo);
  concat_qk_bias<<<dim3(4), 512, 0, stream>>>(b_bq, b_bk, qkbias);
  bias2_p1<<<dim3(16), 256, 0, stream>>>(b_bo, W1, partial);
  bias2_p2<<<dim3(2), 256, 0, stream>>>(b1, partial, bias2);
  sentprep<<<dim3(56), 512, 0, stream>>>(t_Wq, t_bq, t_Wo, kemo, vemo, Wqk, VWo, sbias);
  // Btbig[o][i*512+n] = (Wo_i . W1_i)^T, batched over i via z
  gemm_bt64<true, 0><<<dim3(8, 4, 4), 256, 0, stream>>>(wT + 14 * SL, bWo_bf, nullptr, Btbig,
                                                        512, 512, 2048, 2048, 512, SL, 512);

  // fused sentiment block -> h_t (bf16)
  sent_fused<<<dim3(512), 256, 0, stream>>>(xb, x, Wqk, VWo, sbias, t_bo, t_ln_g, t_ln_b, htb);

  // merged V^T for all 4 branches: [2048][16384] = WvT_all @ htb^T + bv
  gemm_bt64<true, 2><<<dim3(256, 16), 256, 0, stream>>>(wT + 10 * SL, htb, b_bv,
                                                        vtb_all, 16384, 512, 512, 16384, 0, 0, 0);

  // four masked attention branches
  for (int i = 0; i < 4; ++i) {
    gemm_bt<true, 1><<<dim3(8, 128), 256, 0, stream>>>(htb, wT + (2 + 2 * i) * SL, qkbias + i * 1024,
                                                       qkb, 1024, 512, 512, 1024, 0, 0, 0);
    dim3 ag(512, 8);
    const __bf16* vti = vtb_all + (size_t)i * 512 * M_;
    switch (i) {
      case 0: attn_branch<0><<<ag, 256, 0, stream>>>(qkb, qkb + 512, vti, ctxa + 0 * 512, lengths, speakers, 1024, 2048); break;
      case 1: attn_branch<1><<<ag, 256, 0, stream>>>(qkb, qkb + 512, vti, ctxa + 1 * 512, lengths, speakers, 1024, 2048); break;
      case 2: attn_branch<2><<<ag, 256, 0, stream>>>(qkb, qkb + 512, vti, ctxa + 2 * 512, lengths, speakers, 1024, 2048); break;
      case 3: attn_branch<3><<<ag, 256, 0, stream>>>(qkb, qkb + 512, vti, ctxa + 3 * 512, lengths, speakers, 1024, 2048); break;
    }
  }

  // fused (cat @ blockdiag(Wo) @ W1): one K=2048 GEMM -> bf16
  gemm_bt64<true, 1><<<dim3(8, 128), 256, 0, stream>>>(ctxa, Btbig, bias2, tmpb, 512, 2048, 2048, 512, 0, 0, 0);
  ln2_bb<<<dim3(16384), 256, 0, stream>>>(tmpb, htb, ln2_g, ln2_b, heb);
  gemm_bt64<false, 0><<<dim3(8, 128), 256, 0, stream>>>(heb, wT + 0 * SL, nullptr, (float*)d_out, 512, 512, 512, 512, 0, 0, 0);
}

// Round 7
// 597.503 us; speedup vs baseline: 1.4948x; 1.4948x over previous
//
#include <hip/hip_runtime.h>

#define B_  64
#define T_  256
#define H_  512
#define NH_ 8
#define DH_ 64
#define M_  16384
#define SL  262144  // 512*512 elements per weight slot

typedef float  f32x4 __attribute__((ext_vector_type(4)));
typedef float  f32x2 __attribute__((ext_vector_type(2)));
typedef __bf16 b16x8 __attribute__((ext_vector_type(8)));
typedef __bf16 b16x4 __attribute__((ext_vector_type(4)));
typedef __bf16 b16x2 __attribute__((ext_vector_type(2)));

__device__ __forceinline__ void gload16(const void* g, void* l) {
  __builtin_amdgcn_global_load_lds((const __attribute__((address_space(1))) void*)g,
                                   (__attribute__((address_space(3))) void*)l, 16, 0, 0);
}

// ---------------- fp32 -> bf16 convert ----------------
__global__ __launch_bounds__(256) void cvt_f32_bf16_k(const float* __restrict__ in,
                                                      __bf16* __restrict__ out) {
  size_t i = ((size_t)blockIdx.x * 256 + threadIdx.x) * 4;
  f32x4 v = *(const f32x4*)(in + i);
  b16x4 o;
  o[0] = (__bf16)v[0]; o[1] = (__bf16)v[1]; o[2] = (__bf16)v[2]; o[3] = (__bf16)v[3];
  *(b16x4*)(out + i) = o;
}

// ---------------- batched weight transpose: up to 15 (512x512) slices ----------------
struct TP15 { const float* src[15]; int slot[15]; };
__global__ __launch_bounds__(256) void transpose_cvt15(TP15 p, __bf16* __restrict__ wT) {
  __shared__ float tile[32][33];
  const float* in = p.src[blockIdx.z];
  __bf16* out = wT + (size_t)p.slot[blockIdx.z] * SL;
  int c0 = blockIdx.x * 32, r0 = blockIdx.y * 32;
  int tx = threadIdx.x & 31, ty = threadIdx.x >> 5;
  for (int yy = ty; yy < 32; yy += 8)
    tile[yy][tx] = in[(size_t)(r0 + yy) * 512 + c0 + tx];
  __syncthreads();
  for (int yy = ty; yy < 32; yy += 8)
    out[(size_t)(c0 + yy) * 512 + r0 + tx] = (__bf16)tile[tx][yy];
}

// ---------------- generic transpose + convert (for W1: 2048x512) ----------------
__global__ __launch_bounds__(256) void transpose_cvt(const float* __restrict__ in,
                                                     __bf16* __restrict__ out, int R, int C) {
  __shared__ float tile[32][33];
  int c0 = blockIdx.x * 32, r0 = blockIdx.y * 32;
  int tx = threadIdx.x & 31, ty = threadIdx.x >> 5;
  for (int yy = ty; yy < 32; yy += 8)
    tile[yy][tx] = in[(size_t)(r0 + yy) * C + c0 + tx];
  __syncthreads();
  for (int yy = ty; yy < 32; yy += 8)
    out[(size_t)(c0 + yy) * R + r0 + tx] = (__bf16)tile[tx][yy];
}

// ---------------- emotion K/V: (7,512) = emo @ W + b ----------------
__global__ __launch_bounds__(512) void emo_kv(const float* __restrict__ emo,
                                              const float* __restrict__ Wk, const float* __restrict__ bk,
                                              const float* __restrict__ Wv, const float* __restrict__ bv,
                                              float* __restrict__ kout, float* __restrict__ vout) {
  int e = blockIdx.x, n = threadIdx.x;
  const float* W = blockIdx.y ? Wv : Wk;
  const float* bb = blockIdx.y ? bv : bk;
  float* o = blockIdx.y ? vout : kout;
  float acc = 0.f;
  for (int kk = 0; kk < 512; ++kk) acc += emo[e * 512 + kk] * W[kk * 512 + n];
  o[e * 512 + n] = acc + bb[n];
}

// ---------------- sentiment precompute (bf16, scale folded) ----------------
// Wqk_bf[he][t] = 0.125 * sum_d Wq[t][h*64+d] * kemo[e][h*64+d]     (he = h*7+e)
// VWo_bf[t][h*8+e] = sum_d vemo[e][h*64+d] * Wo[h*64+d][t]; pad e=7 -> 0
// sbias[he] = 0.125 * sum_d bq[h*64+d] * kemo[e][h*64+d]
__global__ __launch_bounds__(512) void sentprep(const float* __restrict__ Wq,
                                                const float* __restrict__ bq,
                                                const float* __restrict__ Wo,
                                                const float* __restrict__ kemo,
                                                const float* __restrict__ vemo,
                                                __bf16* __restrict__ Wqk_bf,
                                                __bf16* __restrict__ VWo_bf,
                                                float* __restrict__ sbias) {
  const int he = blockIdx.x, h = he / 7, e = he % 7;
  const int t = threadIdx.x;
  const float* kp = kemo + e * 512 + h * 64;
  const float* wqr = Wq + (size_t)t * 512 + h * 64;
  float a = 0.f;
#pragma unroll 8
  for (int d = 0; d < 64; ++d) a += wqr[d] * kp[d];
  Wqk_bf[he * 512 + t] = (__bf16)(a * 0.125f);
  const float* vp = vemo + e * 512 + h * 64;
  float v = 0.f;
#pragma unroll 8
  for (int d = 0; d < 64; ++d) v += vp[d] * Wo[(size_t)(h * 64 + d) * 512 + t];
  VWo_bf[t * 64 + h * 8 + e] = (__bf16)v;
  if (e == 0) VWo_bf[t * 64 + h * 8 + 7] = (__bf16)0.f;
  if (t < 8 && he == 0) {  // zero pad rows 56..63 of Wqk_bf lazily via first block? no: see below
  }
  if (t == 0) {
    float s = 0.f;
    for (int d = 0; d < 64; ++d) s += bq[h * 64 + d] * kp[d];
    sbias[he] = s * 0.125f;
  }
}

// zero pad rows 56..63 of Wqk_bf and sbias (avoid NaN garbage on first call)
__global__ __launch_bounds__(512) void sentpad(__bf16* __restrict__ Wqk_bf,
                                               float* __restrict__ sbias) {
  int r = 56 + blockIdx.x;   // 8 blocks
  Wqk_bf[r * 512 + threadIdx.x] = (__bf16)0.f;
  if (threadIdx.x == 0) sbias[r] = 0.f;
}

// ---------------- bias helpers ----------------
__global__ __launch_bounds__(512) void concat_qk_bias(const float* __restrict__ bq,
                                                      const float* __restrict__ bk,
                                                      float* __restrict__ out) {
  int i = blockIdx.x, t = threadIdx.x;
  out[i * 1024 + t]       = bq[i * 512 + t];
  out[i * 1024 + 512 + t] = bk[i * 512 + t];
}

__global__ __launch_bounds__(256) void bias2_p1(const float* __restrict__ bo,
                                                const float* __restrict__ W1,
                                                float* __restrict__ partial) {
  int p = blockIdx.x, t = threadIdx.x;
  float a0 = 0.f, a1 = 0.f;
  for (int g = p * 128; g < p * 128 + 128; ++g) {
    float bg = bo[g];
    a0 += bg * W1[(size_t)g * 512 + t];
    a1 += bg * W1[(size_t)g * 512 + 256 + t];
  }
  partial[p * 512 + t] = a0;
  partial[p * 512 + 256 + t] = a1;
}

__global__ __launch_bounds__(256) void bias2_p2(const float* __restrict__ b1,
                                                const float* __restrict__ partial,
                                                float* __restrict__ out) {
  int o = blockIdx.x * 256 + threadIdx.x;
  float acc = b1[o];
#pragma unroll
  for (int p = 0; p < 16; ++p) acc += partial[p * 512 + o];
  out[o] = acc;
}

// ---------------- MFMA GEMM 128x128 (m97 structure + XCD swizzle) ----------------
template<bool OB, int BM>
__global__ __launch_bounds__(256) void gemm_bt(const __bf16* __restrict__ A,
                                               const __bf16* __restrict__ Bt,
                                               const float* __restrict__ bias,
                                               void* __restrict__ Cv,
                                               int N, int K, int lda, int ldc,
                                               size_t zA, size_t zB, size_t zC) {
  __shared__ __attribute__((aligned(16))) __bf16 As[128 * 32];
  __shared__ __attribute__((aligned(16))) __bf16 Bs[128 * 32];
  A  += (size_t)blockIdx.z * zA;
  Bt += (size_t)blockIdx.z * zB;
  char* Cb = (char*)Cv + (size_t)blockIdx.z * zC * (OB ? 2 : 4);
  const int gx = gridDim.x;
  const int nwg = gx * gridDim.y;
  const int bid = blockIdx.y * gx + blockIdx.x;
  const int cpx = nwg >> 3;
  const int swz = (bid & 7) * cpx + (bid >> 3);
  const int bx = swz % gx, by = swz / gx;
  const int tid = threadIdx.x, lane = tid & 63, wid = tid >> 6;
  const int wm = wid & 1, wn = wid >> 1;
  const int m0 = by * 128, n0 = bx * 128;
  const int l15 = lane & 15, l16 = lane >> 4;
  const int r0 = tid >> 2, o0 = (tid & 3) * 8;
  const __bf16* a0 = A + (size_t)(m0 + r0) * lda + o0;
  const __bf16* a1 = A + (size_t)(m0 + 64 + r0) * lda + o0;
  const __bf16* bp0 = Bt + (size_t)(n0 + r0) * K + o0;
  const __bf16* bp1 = Bt + (size_t)(n0 + 64 + r0) * K + o0;
  char* AsW = (char*)As + wid * 1024;
  char* BsW = (char*)Bs + wid * 1024;
  f32x4 acc[4][4] = {};
  for (int k0 = 0; k0 < K; k0 += 32) {
    gload16(a0 + k0, AsW);
    gload16(a1 + k0, AsW + 4096);
    gload16(bp0 + k0, BsW);
    gload16(bp1 + k0, BsW + 4096);
    __syncthreads();
    b16x8 af[4], bf[4];
#pragma unroll
    for (int m = 0; m < 4; ++m) af[m] = *(const b16x8*)&As[(wm * 64 + m * 16 + l15) * 32 + l16 * 8];
#pragma unroll
    for (int n = 0; n < 4; ++n) bf[n] = *(const b16x8*)&Bs[(wn * 64 + n * 16 + l15) * 32 + l16 * 8];
#pragma unroll
    for (int m = 0; m < 4; ++m)
#pragma unroll
      for (int n = 0; n < 4; ++n)
        acc[m][n] = __builtin_amdgcn_mfma_f32_16x16x32_bf16(af[m], bf[n], acc[m][n], 0, 0, 0);
    __syncthreads();
  }
  const int rbase = m0 + wm * 64 + l16 * 4;
  const int cb = n0 + wn * 64 + l15;
#pragma unroll
  for (int n = 0; n < 4; ++n) {
    int gc = cb + n * 16;
    float bc = (BM == 1) ? bias[gc] : 0.0f;
#pragma unroll
    for (int m = 0; m < 4; ++m) {
#pragma unroll
      for (int rr = 0; rr < 4; ++rr) {
        int gr = rbase + m * 16 + rr;
        float val = acc[m][n][rr] + ((BM == 2) ? bias[gr] : bc);
        if (OB) ((__bf16*)Cb)[(size_t)gr * ldc + gc] = (__bf16)val;
        else    ((float*)Cb)[(size_t)gr * ldc + gc] = val;
      }
    }
  }
}

// ---------------- MFMA GEMM 128x64 (higher occupancy for skinny N) ----------------
template<bool OB, int BM>
__global__ __launch_bounds__(256) void gemm_bt64(const __bf16* __restrict__ A,
                                                 const __bf16* __restrict__ Bt,
                                                 const float* __restrict__ bias,
                                                 void* __restrict__ Cv,
                                                 int N, int K, int lda, int ldc,
                                                 size_t zA, size_t zB, size_t zC) {
  __shared__ __attribute__((aligned(16))) __bf16 As[128 * 32];
  __shared__ __attribute__((aligned(16))) __bf16 Bs[64 * 32];
  A  += (size_t)blockIdx.z * zA;
  Bt += (size_t)blockIdx.z * zB;
  char* Cb = (char*)Cv + (size_t)blockIdx.z * zC * (OB ? 2 : 4);
  const int gx = gridDim.x;
  const int nwg = gx * gridDim.y;
  const int bid = blockIdx.y * gx + blockIdx.x;
  const int cpx = nwg >> 3;
  const int swz = (bid & 7) * cpx + (bid >> 3);
  const int bx = swz % gx, by = swz / gx;
  const int tid = threadIdx.x, lane = tid & 63, wid = tid >> 6;
  const int m0 = by * 128, n0 = bx * 64;
  const int l15 = lane & 15, l16 = lane >> 4;
  const int r0 = tid >> 2, o0 = (tid & 3) * 8;
  const __bf16* a0 = A + (size_t)(m0 + r0) * lda + o0;
  const __bf16* a1 = A + (size_t)(m0 + 64 + r0) * lda + o0;
  const __bf16* bp0 = Bt + (size_t)(n0 + r0) * K + o0;
  char* AsW = (char*)As + wid * 1024;
  char* BsW = (char*)Bs + wid * 1024;
  f32x4 acc[2][4] = {};
  for (int k0 = 0; k0 < K; k0 += 32) {
    gload16(a0 + k0, AsW);
    gload16(a1 + k0, AsW + 4096);
    gload16(bp0 + k0, BsW);
    __syncthreads();
    b16x8 af[2], bf[4];
#pragma unroll
    for (int m = 0; m < 2; ++m) af[m] = *(const b16x8*)&As[(wid * 32 + m * 16 + l15) * 32 + l16 * 8];
#pragma unroll
    for (int n = 0; n < 4; ++n) bf[n] = *(const b16x8*)&Bs[(n * 16 + l15) * 32 + l16 * 8];
#pragma unroll
    for (int m = 0; m < 2; ++m)
#pragma unroll
      for (int n = 0; n < 4; ++n)
        acc[m][n] = __builtin_amdgcn_mfma_f32_16x16x32_bf16(af[m], bf[n], acc[m][n], 0, 0, 0);
    __syncthreads();
  }
  const int rbase = m0 + wid * 32 + l16 * 4;
  const int cb = n0 + l15;
#pragma unroll
  for (int n = 0; n < 4; ++n) {
    int gc = cb + n * 16;
    float bc = (BM == 1) ? bias[gc] : 0.0f;
#pragma unroll
    for (int m = 0; m < 2; ++m) {
#pragma unroll
      for (int rr = 0; rr < 4; ++rr) {
        int gr = rbase + m * 16 + rr;
        float val = acc[m][n][rr] + ((BM == 2) ? bias[gr] : bc);
        if (OB) ((__bf16*)Cb)[(size_t)gr * ldc + gc] = (__bf16)val;
        else    ((float*)Cb)[(size_t)gr * ldc + gc] = val;
      }
    }
  }
}

// ---------------- per-(token,head) 7-wide softmax; emits normalized P bf16 padded ----------------
__global__ __launch_bounds__(256) void softmax7(const float* __restrict__ scores,
                                                __bf16* __restrict__ P) {
  int idx = blockIdx.x * 256 + threadIdx.x;
  int m = idx >> 3, h = idx & 7;
  const float* s = scores + (size_t)m * 64 + h * 7;
  float v[7], mx = -3.4e38f;
#pragma unroll
  for (int e = 0; e < 7; ++e) { v[e] = s[e]; mx = fmaxf(mx, v[e]); }
  float sum = 0.f;
#pragma unroll
  for (int e = 0; e < 7; ++e) { v[e] = __expf(v[e] - mx); sum += v[e]; }
  float inv = 1.f / sum;
  __bf16* o = P + (size_t)m * 64 + h * 8;
#pragma unroll
  for (int e = 0; e < 7; ++e) o[e] = (__bf16)(v[e] * inv);
  o[7] = (__bf16)0.f;
}

// ---------------- bf16 pre + fp32 res LayerNorm -> bf16 ----------------
__global__ __launch_bounds__(256) void ln1_bf(const __bf16* __restrict__ pre,
                                              const float* __restrict__ res,
                                              const float* __restrict__ g,
                                              const float* __restrict__ bt,
                                              __bf16* __restrict__ ob) {
  int row = blockIdx.x, t = threadIdx.x;
  size_t base = (size_t)row * 512;
  b16x2 p2 = *(const b16x2*)(pre + base + 2 * t);
  f32x2 r2 = *(const f32x2*)(res + base + 2 * t);
  float v0 = (float)p2[0] + r2[0];
  float v1 = (float)p2[1] + r2[1];
  float s = v0 + v1, q = v0 * v0 + v1 * v1;
#pragma unroll
  for (int off = 32; off; off >>= 1) { s += __shfl_xor(s, off); q += __shfl_xor(q, off); }
  __shared__ float ls[4], lq[4];
  int wid = t >> 6, lane = t & 63;
  if (lane == 0) { ls[wid] = s; lq[wid] = q; }
  __syncthreads();
  s = ls[0] + ls[1] + ls[2] + ls[3];
  q = lq[0] + lq[1] + lq[2] + lq[3];
  float mean = s * (1.f / 512.f);
  float var = q * (1.f / 512.f) - mean * mean;
  float rstd = rsqrtf(fmaxf(var, 0.f) + 1e-12f);
  b16x2 o;
  o[0] = (__bf16)((v0 - mean) * rstd * g[2 * t] + bt[2 * t]);
  o[1] = (__bf16)((v1 - mean) * rstd * g[2 * t + 1] + bt[2 * t + 1]);
  *(b16x2*)(ob + base + 2 * t) = o;
}

// ---------------- bf16+bf16 residual LayerNorm ----------------
__global__ __launch_bounds__(256) void ln2_bb(const __bf16* __restrict__ pre,
                                              const __bf16* __restrict__ res,
                                              const float* __restrict__ g,
                                              const float* __restrict__ bt,
                                              __bf16* __restrict__ ob) {
  int row = blockIdx.x, t = threadIdx.x;
  size_t base = (size_t)row * 512;
  b16x2 p2 = *(const b16x2*)(pre + base + 2 * t);
  b16x2 r2 = *(const b16x2*)(res + base + 2 * t);
  float v0 = (float)p2[0] + (float)r2[0];
  float v1 = (float)p2[1] + (float)r2[1];
  float s = v0 + v1, q = v0 * v0 + v1 * v1;
#pragma unroll
  for (int off = 32; off; off >>= 1) { s += __shfl_xor(s, off); q += __shfl_xor(q, off); }
  __shared__ float ls[4], lq[4];
  int wid = t >> 6, lane = t & 63;
  if (lane == 0) { ls[wid] = s; lq[wid] = q; }
  __syncthreads();
  s = ls[0] + ls[1] + ls[2] + ls[3];
  q = lq[0] + lq[1] + lq[2] + lq[3];
  float mean = s * (1.f / 512.f);
  float var = q * (1.f / 512.f) - mean * mean;
  float rstd = rsqrtf(fmaxf(var, 0.f) + 1e-12f);
  b16x2 o;
  o[0] = (__bf16)((v0 - mean) * rstd * g[2 * t] + bt[2 * t]);
  o[1] = (__bf16)((v1 - mean) * rstd * g[2 * t + 1] + bt[2 * t + 1]);
  *(b16x2*)(ob + base + 2 * t) = o;
}

// ---------------- fused masked attention; P overlays Ks; V prefetch ----------------
template<int BR>
__global__ __launch_bounds__(256, 4) void attn_branch(const __bf16* __restrict__ q,
                                                      const __bf16* __restrict__ kk_,
                                                      const __bf16* __restrict__ vt,
                                                      __bf16* __restrict__ ctx,
                                                      const int* __restrict__ lengths,
                                                      const int* __restrict__ speakers,
                                                      int sqk, int so) {
  __shared__ __attribute__((aligned(16))) __bf16 Ks[256 * 64];
  __shared__ float redM[2][32];
  __shared__ float redS[2][32];
  __shared__ float rowinv[32];
  __shared__ int spk[256];
  const int tid = threadIdx.x, lane = tid & 63, wid = tid >> 6;
  const int l15 = lane & 15, l16 = lane >> 4;
  const int bh = blockIdx.x, q0 = blockIdx.y * 32;
  const int b = bh >> 3, h = bh & 7;
  const int wq = wid & 1, wk = wid >> 1;
  const int mh = wid & 1, nh = wid >> 1;
  const __bf16* vb2 = vt + (size_t)(h * DH_) * M_ + b * T_;

  {
    const size_t kb0 = (size_t)(b * T_) * sqk + h * DH_;
    const int rsub = lane >> 3, slot = lane & 7;
#pragma unroll
    for (int j = 0; j < 8; ++j) {
      int row = (j * 4 + wid) * 8 + rsub;
      gload16(kk_ + kb0 + (size_t)row * sqk + ((slot ^ (row & 7)) * 8),
              (char*)Ks + (j * 4 + wid) * 1024);
    }
  }
  spk[tid] = speakers[b * T_ + tid];
  b16x8 af0, af1;
  {
    const __bf16* qr = q + (size_t)(b * T_ + q0 + wq * 16 + l15) * sqk + h * DH_;
    af0 = *(const b16x8*)(qr + l16 * 8);
    af1 = *(const b16x8*)(qr + 32 + l16 * 8);
  }
  __syncthreads();

  f32x4 sa[4][2] = {};
#pragma unroll
  for (int kc = 0; kc < 4; ++kc) {
#pragma unroll
    for (int nn = 0; nn < 2; ++nn) {
      int krw = kc * 64 + wk * 32 + nn * 16 + l15;
      b16x8 b0 = *(const b16x8*)((char*)Ks + krw * 128 + ((l16 ^ (krw & 7)) * 16));
      sa[kc][nn] = __builtin_amdgcn_mfma_f32_16x16x32_bf16(af0, b0, sa[kc][nn], 0, 0, 0);
      b16x8 b1 = *(const b16x8*)((char*)Ks + krw * 128 + (((4 + l16) ^ (krw & 7)) * 16));
      sa[kc][nn] = __builtin_amdgcn_mfma_f32_16x16x32_bf16(af1, b1, sa[kc][nn], 0, 0, 0);
    }
  }

  b16x8 vpre[2][2];
#pragma unroll
  for (int kt = 0; kt < 2; ++kt)
#pragma unroll
    for (int n = 0; n < 2; ++n) {
      int d = nh * 32 + n * 16 + l15;
      vpre[kt][n] = *(const b16x8*)(vb2 + (size_t)d * M_ + kt * 32 + l16 * 8);
    }

  const int L = lengths[b];
  const int rloc = wq * 16 + l16 * 4;
  float ev[4][8];
  float mx[4];
#pragma unroll
  for (int rr = 0; rr < 4; ++rr) {
    const int j = q0 + rloc + rr;
    const int spj = spk[j];
    const bool rv = j < L;
    mx[rr] = -3.4e38f;
#pragma unroll
    for (int kc = 0; kc < 4; ++kc)
#pragma unroll
      for (int nn = 0; nn < 2; ++nn) {
        int c = kc * 64 + wk * 32 + nn * 16 + l15;
        int dj = j - c;
        bool ok;
        if (BR == 0)      ok = (c < L);
        else if (BR == 1) ok = rv && (c < L) && (dj <= 2) && (dj >= -2);
        else if (BR == 2) ok = rv && (spk[c] == spj);
        else              ok = rv && (spk[c] != spj) && (c < L);
        float s = sa[kc][nn][rr] * 0.125f + (ok ? 0.0f : -10000.0f);
        ev[rr][kc * 2 + nn] = s;
        mx[rr] = fmaxf(mx[rr], s);
      }
    mx[rr] = fmaxf(mx[rr], __shfl_xor(mx[rr], 1));
    mx[rr] = fmaxf(mx[rr], __shfl_xor(mx[rr], 2));
    mx[rr] = fmaxf(mx[rr], __shfl_xor(mx[rr], 4));
    mx[rr] = fmaxf(mx[rr], __shfl_xor(mx[rr], 8));
  }
  if (l15 == 0) {
#pragma unroll
    for (int rr = 0; rr < 4; ++rr) redM[wk][rloc + rr] = mx[rr];
  }
  __syncthreads();
  float sm[4];
#pragma unroll
  for (int rr = 0; rr < 4; ++rr) {
    float mxf = fmaxf(redM[0][rloc + rr], redM[1][rloc + rr]);
    float s = 0.f;
#pragma unroll
    for (int i = 0; i < 8; ++i) { float e = __expf(ev[rr][i] - mxf); ev[rr][i] = e; s += e; }
    s += __shfl_xor(s, 1); s += __shfl_xor(s, 2); s += __shfl_xor(s, 4); s += __shfl_xor(s, 8);
    sm[rr] = s;
  }
  if (l15 == 0) {
#pragma unroll
    for (int rr = 0; rr < 4; ++rr) redS[wk][rloc + rr] = sm[rr];
  }
  __syncthreads();
  __bf16* P = (__bf16*)Ks;
#pragma unroll
  for (int rr = 0; rr < 4; ++rr) {
    if (wk == 0 && l15 == 0)
      rowinv[rloc + rr] = 1.0f / (redS[0][rloc + rr] + redS[1][rloc + rr]);
#pragma unroll
    for (int kc = 0; kc < 4; ++kc)
#pragma unroll
      for (int nn = 0; nn < 2; ++nn)
        P[(rloc + rr) * 260 + kc * 64 + wk * 32 + nn * 16 + l15] = (__bf16)ev[rr][kc * 2 + nn];
  }
  __syncthreads();

  f32x4 oa[2] = {};
#pragma unroll
  for (int kt = 0; kt < 8; ++kt) {
    b16x8 afp = *(const b16x8*)(P + (mh * 16 + l15) * 260 + kt * 32 + l16 * 8);
#pragma unroll
    for (int n = 0; n < 2; ++n) {
      b16x8 bfr;
      if (kt < 2) bfr = vpre[kt][n];
      else {
        int d = nh * 32 + n * 16 + l15;
        bfr = *(const b16x8*)(vb2 + (size_t)d * M_ + kt * 32 + l16 * 8);
      }
      oa[n] = __builtin_amdgcn_mfma_f32_16x16x32_bf16(afp, bfr, oa[n], 0, 0, 0);
    }
  }
#pragma unroll
  for (int n = 0; n < 2; ++n)
#pragma unroll
    for (int rr = 0; rr < 4; ++rr) {
      int row = mh * 16 + l16 * 4 + rr;
      ctx[(size_t)(b * T_ + q0 + row) * so + h * DH_ + nh * 32 + n * 16 + l15]
          = (__bf16)(oa[n][rr] * rowinv[row]);
    }
}

// ============================================================================
extern "C" void kernel_launch(void* const* d_in, const int* in_sizes, int n_in,
                              void* d_out, int out_size, void* d_ws, size_t ws_size,
                              hipStream_t stream) {
  const float* x        = (const float*)d_in[0];
  const int*   lengths  = (const int*)d_in[1];
  const int*   speakers = (const int*)d_in[2];
  const float* emo      = (const float*)d_in[3];
  const float* t_Wq = (const float*)d_in[4];
  const float* t_bq = (const float*)d_in[5];
  const float* t_Wk = (const float*)d_in[6];
  const float* t_bk = (const float*)d_in[7];
  const float* t_Wv = (const float*)d_in[8];
  const float* t_bv = (const float*)d_in[9];
  const float* t_Wo = (const float*)d_in[10];
  const float* t_bo = (const float*)d_in[11];
  const float* t_ln_g = (const float*)d_in[12];
  const float* t_ln_b = (const float*)d_in[13];
  const float* b_Wq = (const float*)d_in[14];
  const float* b_bq = (const float*)d_in[15];
  const float* b_Wk = (const float*)d_in[16];
  const float* b_bk = (const float*)d_in[17];
  const float* b_Wv = (const float*)d_in[18];
  const float* b_bv = (const float*)d_in[19];
  const float* b_Wo = (const float*)d_in[20];
  const float* b_bo = (const float*)d_in[21];
  const float* W1   = (const float*)d_in[22];
  const float* b1   = (const float*)d_in[23];
  const float* ln2_g = (const float*)d_in[24];
  const float* ln2_b = (const float*)d_in[25];
  const float* W2   = (const float*)d_in[26];

  if (ws_size < 232314880) return;

  char* ws = (char*)d_ws;
  // wT slots: 0=W2t  [2+2i,3+2i]=WqT_i/WkT_i  [10+i]=WvT_i  14..17=W1t
  __bf16* wT      = (__bf16*)(ws);              // 18 slots = 9,437,184 B
  __bf16* bWo_bf  = (__bf16*)(ws + 9437184);
  __bf16* Btbig   = (__bf16*)(ws + 11534336);
  float*  qkbias  = (float*)(ws + 13631488);
  float*  bias2   = (float*)(ws + 13647872);
  float*  kemo    = (float*)(ws + 13649920);
  float*  vemo    = (float*)(ws + 13664256);
  __bf16* Wqk_bf  = (__bf16*)(ws + 13678592);   // [64][512] bf16
  __bf16* VWo_bf  = (__bf16*)(ws + 13744128);   // [512][64] bf16
  float*  sbias   = (float*)(ws + 13809664);    // [64]
  __bf16* xb      = (__bf16*)(ws + 13908224);   // reused as heb after sentiment block
  __bf16* htb     = (__bf16*)(ws + 30685440);
  __bf16* qkb     = (__bf16*)(ws + 47462656);   // [16384][1024] per branch; overlays below
  __bf16* vtb_all = (__bf16*)(ws + 81017088);   // [2048][16384]
  __bf16* ctxa    = (__bf16*)(ws + 148125952);  // [16384][2048]
  __bf16* heb  = xb;
  __bf16* tmpb = qkb;                 // K2048 output; qkb dead after last attn
  float*  partial = (float*)qkb;      // bias2 scratch, dead before sentiment
  float*  scores  = (float*)qkb;      // [16384][64] fp32 (4 MB), dead before qk proj
  __bf16* Pmat    = (__bf16*)(ws + 47462656 + 4194304);   // [16384][64] bf16 (2 MB)
  __bf16* sctx    = (__bf16*)(ws + 47462656 + 8388608);   // [16384][512] bf16 (16 MB)

  // conversions + transposes
  cvt_f32_bf16_k<<<dim3(8192), 256, 0, stream>>>(x, xb);
  cvt_f32_bf16_k<<<dim3(1024), 256, 0, stream>>>(b_Wo, bWo_bf);
  {
    TP15 p;
    const float* srcs[13] = {b_Wq, b_Wq + SL, b_Wq + 2 * SL, b_Wq + 3 * SL,
                             b_Wk, b_Wk + SL, b_Wk + 2 * SL, b_Wk + 3 * SL,
                             b_Wv, b_Wv + SL, b_Wv + 2 * SL, b_Wv + 3 * SL,
                             W2};
    const int slots[13] = {2, 4, 6, 8, 3, 5, 7, 9, 10, 11, 12, 13, 0};
    for (int i = 0; i < 13; ++i) { p.src[i] = srcs[i]; p.slot[i] = slots[i]; }
    for (int i = 13; i < 15; ++i) { p.src[i] = W2; p.slot[i] = 0; }
    transpose_cvt15<<<dim3(16, 16, 13), 256, 0, stream>>>(p, wT);
  }
  transpose_cvt<<<dim3(16, 64), 256, 0, stream>>>(W1, wT + 14 * SL, 2048, 512);
  emo_kv<<<dim3(7, 2), 512, 0, stream>>>(emo, t_Wk, t_bk, t_Wv, t_bv, kemo, vemo);
  concat_qk_bias<<<dim3(4), 512, 0, stream>>>(b_bq, b_bk, qkbias);
  bias2_p1<<<dim3(16), 256, 0, stream>>>(b_bo, W1, partial);
  bias2_p2<<<dim3(2), 256, 0, stream>>>(b1, partial, bias2);
  sentprep<<<dim3(56), 512, 0, stream>>>(t_Wq, t_bq, t_Wo, kemo, vemo, Wqk_bf, VWo_bf, sbias);
  sentpad<<<dim3(8), 512, 0, stream>>>(Wqk_bf, sbias);
  // Btbig[o][i*512+n] = (Wo_i . W1_i)^T, batched over i via z
  gemm_bt64<true, 0><<<dim3(8, 4, 4), 256, 0, stream>>>(wT + 14 * SL, bWo_bf, nullptr, Btbig,
                                                        512, 512, 2048, 2048, 512, SL, 512);

  // sentiment block on MFMA: scores -> softmax -> P@VWo -> LN
  gemm_bt64<false, 1><<<dim3(1, 128), 256, 0, stream>>>(xb, Wqk_bf, sbias, scores,
                                                        64, 512, 512, 64, 0, 0, 0);
  softmax7<<<dim3(512), 256, 0, stream>>>(scores, Pmat);
  gemm_bt64<true, 1><<<dim3(8, 128), 256, 0, stream>>>(Pmat, VWo_bf, t_bo, sctx,
                                                       512, 64, 64, 512, 0, 0, 0);
  ln1_bf<<<dim3(16384), 256, 0, stream>>>(sctx, x, t_ln_g, t_ln_b, htb);

  // merged V^T for all 4 branches: [2048][16384] = WvT_all @ htb^T + bv
  gemm_bt64<true, 2><<<dim3(256, 16), 256, 0, stream>>>(wT + 10 * SL, htb, b_bv,
                                                        vtb_all, 16384, 512, 512, 16384, 0, 0, 0);

  // four masked attention branches
  for (int i = 0; i < 4; ++i) {
    gemm_bt<true, 1><<<dim3(8, 128), 256, 0, stream>>>(htb, wT + (2 + 2 * i) * SL, qkbias + i * 1024,
                                                       qkb, 1024, 512, 512, 1024, 0, 0, 0);
    dim3 ag(512, 8);
    const __bf16* vti = vtb_all + (size_t)i * 512 * M_;
    switch (i) {
      case 0: attn_branch<0><<<ag, 256, 0, stream>>>(qkb, qkb + 512, vti, ctxa + 0 * 512, lengths, speakers, 1024, 2048); break;
      case 1: attn_branch<1><<<ag, 256, 0, stream>>>(qkb, qkb + 512, vti, ctxa + 1 * 512, lengths, speakers, 1024, 2048); break;
      case 2: attn_branch<2><<<ag, 256, 0, stream>>>(qkb, qkb + 512, vti, ctxa + 2 * 512, lengths, speakers, 1024, 2048); break;
      case 3: attn_branch<3><<<ag, 256, 0, stream>>>(qkb, qkb + 512, vti, ctxa + 3 * 512, lengths, speakers, 1024, 2048); break;
    }
  }

  // fused (cat @ blockdiag(Wo) @ W1): one K=2048 GEMM -> bf16
  gemm_bt64<true, 1><<<dim3(8, 128), 256, 0, stream>>>(ctxa, Btbig, bias2, tmpb, 512, 2048, 2048, 512, 0, 0, 0);
  ln2_bb<<<dim3(16384), 256, 0, stream>>>(tmpb, htb, ln2_g, ln2_b, heb);
  gemm_bt64<false, 0><<<dim3(8, 128), 256, 0, stream>>>(heb, wT + 0 * SL, nullptr, (float*)d_out, 512, 512, 512, 512, 0, 0, 0);
}

// Round 8
// 590.734 us; speedup vs baseline: 1.5120x; 1.0115x over previous
//
#include <hip/hip_runtime.h>

#define B_  64
#define T_  256
#define H_  512
#define NH_ 8
#define DH_ 64
#define M_  16384
#define SL  262144  // 512*512 elements per weight slot

typedef float  f32x4 __attribute__((ext_vector_type(4)));
typedef float  f32x2 __attribute__((ext_vector_type(2)));
typedef __bf16 b16x8 __attribute__((ext_vector_type(8)));
typedef __bf16 b16x4 __attribute__((ext_vector_type(4)));
typedef __bf16 b16x2 __attribute__((ext_vector_type(2)));

__device__ __forceinline__ void gload16(const void* g, void* l) {
  __builtin_amdgcn_global_load_lds((const __attribute__((address_space(1))) void*)g,
                                   (__attribute__((address_space(3))) void*)l, 16, 0, 0);
}

// ---------------- fp32 -> bf16 convert ----------------
__global__ __launch_bounds__(256) void cvt_f32_bf16_k(const float* __restrict__ in,
                                                      __bf16* __restrict__ out) {
  size_t i = ((size_t)blockIdx.x * 256 + threadIdx.x) * 4;
  f32x4 v = *(const f32x4*)(in + i);
  b16x4 o;
  o[0] = (__bf16)v[0]; o[1] = (__bf16)v[1]; o[2] = (__bf16)v[2]; o[3] = (__bf16)v[3];
  *(b16x4*)(out + i) = o;
}

// ---------------- batched weight transpose: up to 15 (512x512) slices ----------------
struct TP15 { const float* src[15]; int slot[15]; };
__global__ __launch_bounds__(256) void transpose_cvt15(TP15 p, __bf16* __restrict__ wT) {
  __shared__ float tile[32][33];
  const float* in = p.src[blockIdx.z];
  __bf16* out = wT + (size_t)p.slot[blockIdx.z] * SL;
  int c0 = blockIdx.x * 32, r0 = blockIdx.y * 32;
  int tx = threadIdx.x & 31, ty = threadIdx.x >> 5;
  for (int yy = ty; yy < 32; yy += 8)
    tile[yy][tx] = in[(size_t)(r0 + yy) * 512 + c0 + tx];
  __syncthreads();
  for (int yy = ty; yy < 32; yy += 8)
    out[(size_t)(c0 + yy) * 512 + r0 + tx] = (__bf16)tile[tx][yy];
}

// ---------------- generic transpose + convert (for W1: 2048x512) ----------------
__global__ __launch_bounds__(256) void transpose_cvt(const float* __restrict__ in,
                                                     __bf16* __restrict__ out, int R, int C) {
  __shared__ float tile[32][33];
  int c0 = blockIdx.x * 32, r0 = blockIdx.y * 32;
  int tx = threadIdx.x & 31, ty = threadIdx.x >> 5;
  for (int yy = ty; yy < 32; yy += 8)
    tile[yy][tx] = in[(size_t)(r0 + yy) * C + c0 + tx];
  __syncthreads();
  for (int yy = ty; yy < 32; yy += 8)
    out[(size_t)(c0 + yy) * R + r0 + tx] = (__bf16)tile[tx][yy];
}

// ---------------- emotion K/V: (7,512) = emo @ W + b ----------------
__global__ __launch_bounds__(512) void emo_kv(const float* __restrict__ emo,
                                              const float* __restrict__ Wk, const float* __restrict__ bk,
                                              const float* __restrict__ Wv, const float* __restrict__ bv,
                                              float* __restrict__ kout, float* __restrict__ vout) {
  int e = blockIdx.x, n = threadIdx.x;
  const float* W = blockIdx.y ? Wv : Wk;
  const float* bb = blockIdx.y ? bv : bk;
  float* o = blockIdx.y ? vout : kout;
  float acc = 0.f;
  for (int kk = 0; kk < 512; ++kk) acc += emo[e * 512 + kk] * W[kk * 512 + n];
  o[e * 512 + n] = acc + bb[n];
}

// ---------------- sentiment precompute (bf16, scale folded) ----------------
__global__ __launch_bounds__(512) void sentprep(const float* __restrict__ Wq,
                                                const float* __restrict__ bq,
                                                const float* __restrict__ Wo,
                                                const float* __restrict__ kemo,
                                                const float* __restrict__ vemo,
                                                __bf16* __restrict__ Wqk_bf,
                                                __bf16* __restrict__ VWo_bf,
                                                float* __restrict__ sbias) {
  const int he = blockIdx.x, h = he / 7, e = he % 7;
  const int t = threadIdx.x;
  const float* kp = kemo + e * 512 + h * 64;
  const float* wqr = Wq + (size_t)t * 512 + h * 64;
  float a = 0.f;
#pragma unroll 8
  for (int d = 0; d < 64; ++d) a += wqr[d] * kp[d];
  Wqk_bf[he * 512 + t] = (__bf16)(a * 0.125f);
  const float* vp = vemo + e * 512 + h * 64;
  float v = 0.f;
#pragma unroll 8
  for (int d = 0; d < 64; ++d) v += vp[d] * Wo[(size_t)(h * 64 + d) * 512 + t];
  VWo_bf[t * 64 + h * 8 + e] = (__bf16)v;
  if (e == 0) VWo_bf[t * 64 + h * 8 + 7] = (__bf16)0.f;
  if (t == 0) {
    float s = 0.f;
    for (int d = 0; d < 64; ++d) s += bq[h * 64 + d] * kp[d];
    sbias[he] = s * 0.125f;
  }
}

// zero pad rows 56..63 of Wqk_bf and sbias
__global__ __launch_bounds__(512) void sentpad(__bf16* __restrict__ Wqk_bf,
                                               float* __restrict__ sbias) {
  int r = 56 + blockIdx.x;
  Wqk_bf[r * 512 + threadIdx.x] = (__bf16)0.f;
  if (threadIdx.x == 0) sbias[r] = 0.f;
}

// ---------------- bias helpers ----------------
__global__ __launch_bounds__(512) void concat_qk_bias(const float* __restrict__ bq,
                                                      const float* __restrict__ bk,
                                                      float* __restrict__ out) {
  int i = blockIdx.x, t = threadIdx.x;
  out[i * 1024 + t]       = bq[i * 512 + t];
  out[i * 1024 + 512 + t] = bk[i * 512 + t];
}

__global__ __launch_bounds__(256) void bias2_p1(const float* __restrict__ bo,
                                                const float* __restrict__ W1,
                                                float* __restrict__ partial) {
  int p = blockIdx.x, t = threadIdx.x;
  float a0 = 0.f, a1 = 0.f;
  for (int g = p * 128; g < p * 128 + 128; ++g) {
    float bg = bo[g];
    a0 += bg * W1[(size_t)g * 512 + t];
    a1 += bg * W1[(size_t)g * 512 + 256 + t];
  }
  partial[p * 512 + t] = a0;
  partial[p * 512 + 256 + t] = a1;
}

__global__ __launch_bounds__(256) void bias2_p2(const float* __restrict__ b1,
                                                const float* __restrict__ partial,
                                                float* __restrict__ out) {
  int o = blockIdx.x * 256 + threadIdx.x;
  float acc = b1[o];
#pragma unroll
  for (int p = 0; p < 16; ++p) acc += partial[p * 512 + o];
  out[o] = acc;
}

// ---------------- MFMA GEMM 128x64 (m97 structure) ----------------
// BM: 0 = no bias, 1 = column bias, 2 = row bias
// SW: 0 = row-chunk XCD swizzle (A-panel L2-local), 1 = col-chunk (B-panel L2-local)
template<bool OB, int BM, int SW>
__global__ __launch_bounds__(256) void gemm_bt64(const __bf16* __restrict__ A,
                                                 const __bf16* __restrict__ Bt,
                                                 const float* __restrict__ bias,
                                                 void* __restrict__ Cv,
                                                 int N, int K, int lda, int ldc,
                                                 size_t zA, size_t zB, size_t zC) {
  __shared__ __attribute__((aligned(16))) __bf16 As[128 * 32];
  __shared__ __attribute__((aligned(16))) __bf16 Bs[64 * 32];
  A  += (size_t)blockIdx.z * zA;
  Bt += (size_t)blockIdx.z * zB;
  char* Cb = (char*)Cv + (size_t)blockIdx.z * zC * (OB ? 2 : 4);
  const int gx = gridDim.x;
  const int bid = blockIdx.y * gx + blockIdx.x;
  int bx, by;
  if (SW == 0) {
    const int nwg = gx * gridDim.y;
    const int cpx = nwg >> 3;
    const int swz = (bid & 7) * cpx + (bid >> 3);
    bx = swz % gx; by = swz / gx;
  } else {
    // each XCD owns a contiguous bx-chunk (requires gx % 8 == 0)
    const int gxc = gx >> 3;
    const int u = bid >> 3, c = bid & 7;
    bx = c * gxc + u % gxc;
    by = u / gxc;
  }
  const int tid = threadIdx.x, lane = tid & 63, wid = tid >> 6;
  const int m0 = by * 128, n0 = bx * 64;
  const int l15 = lane & 15, l16 = lane >> 4;
  const int r0 = tid >> 2, o0 = (tid & 3) * 8;
  const __bf16* a0 = A + (size_t)(m0 + r0) * lda + o0;
  const __bf16* a1 = A + (size_t)(m0 + 64 + r0) * lda + o0;
  const __bf16* bp0 = Bt + (size_t)(n0 + r0) * K + o0;
  char* AsW = (char*)As + wid * 1024;
  char* BsW = (char*)Bs + wid * 1024;
  f32x4 acc[2][4] = {};
  for (int k0 = 0; k0 < K; k0 += 32) {
    gload16(a0 + k0, AsW);
    gload16(a1 + k0, AsW + 4096);
    gload16(bp0 + k0, BsW);
    __syncthreads();
    b16x8 af[2], bf[4];
#pragma unroll
    for (int m = 0; m < 2; ++m) af[m] = *(const b16x8*)&As[(wid * 32 + m * 16 + l15) * 32 + l16 * 8];
#pragma unroll
    for (int n = 0; n < 4; ++n) bf[n] = *(const b16x8*)&Bs[(n * 16 + l15) * 32 + l16 * 8];
#pragma unroll
    for (int m = 0; m < 2; ++m)
#pragma unroll
      for (int n = 0; n < 4; ++n)
        acc[m][n] = __builtin_amdgcn_mfma_f32_16x16x32_bf16(af[m], bf[n], acc[m][n], 0, 0, 0);
    __syncthreads();
  }
  const int rbase = m0 + wid * 32 + l16 * 4;
  const int cb = n0 + l15;
#pragma unroll
  for (int n = 0; n < 4; ++n) {
    int gc = cb + n * 16;
    float bc = (BM == 1) ? bias[gc] : 0.0f;
#pragma unroll
    for (int m = 0; m < 2; ++m) {
#pragma unroll
      for (int rr = 0; rr < 4; ++rr) {
        int gr = rbase + m * 16 + rr;
        float val = acc[m][n][rr] + ((BM == 2) ? bias[gr] : bc);
        if (OB) ((__bf16*)Cb)[(size_t)gr * ldc + gc] = (__bf16)val;
        else    ((float*)Cb)[(size_t)gr * ldc + gc] = val;
      }
    }
  }
}

// ---------------- per-(token,head) 7-wide softmax; emits normalized P bf16 padded ----------------
__global__ __launch_bounds__(256) void softmax7(const float* __restrict__ scores,
                                                __bf16* __restrict__ P) {
  int idx = blockIdx.x * 256 + threadIdx.x;
  int m = idx >> 3, h = idx & 7;
  const float* s = scores + (size_t)m * 64 + h * 7;
  float v[7], mx = -3.4e38f;
#pragma unroll
  for (int e = 0; e < 7; ++e) { v[e] = s[e]; mx = fmaxf(mx, v[e]); }
  float sum = 0.f;
#pragma unroll
  for (int e = 0; e < 7; ++e) { v[e] = __expf(v[e] - mx); sum += v[e]; }
  float inv = 1.f / sum;
  __bf16* o = P + (size_t)m * 64 + h * 8;
#pragma unroll
  for (int e = 0; e < 7; ++e) o[e] = (__bf16)(v[e] * inv);
  o[7] = (__bf16)0.f;
}

// ---------------- bf16 pre + fp32 res LayerNorm -> bf16 ----------------
__global__ __launch_bounds__(256) void ln1_bf(const __bf16* __restrict__ pre,
                                              const float* __restrict__ res,
                                              const float* __restrict__ g,
                                              const float* __restrict__ bt,
                                              __bf16* __restrict__ ob) {
  int row = blockIdx.x, t = threadIdx.x;
  size_t base = (size_t)row * 512;
  b16x2 p2 = *(const b16x2*)(pre + base + 2 * t);
  f32x2 r2 = *(const f32x2*)(res + base + 2 * t);
  float v0 = (float)p2[0] + r2[0];
  float v1 = (float)p2[1] + r2[1];
  float s = v0 + v1, q = v0 * v0 + v1 * v1;
#pragma unroll
  for (int off = 32; off; off >>= 1) { s += __shfl_xor(s, off); q += __shfl_xor(q, off); }
  __shared__ float ls[4], lq[4];
  int wid = t >> 6, lane = t & 63;
  if (lane == 0) { ls[wid] = s; lq[wid] = q; }
  __syncthreads();
  s = ls[0] + ls[1] + ls[2] + ls[3];
  q = lq[0] + lq[1] + lq[2] + lq[3];
  float mean = s * (1.f / 512.f);
  float var = q * (1.f / 512.f) - mean * mean;
  float rstd = rsqrtf(fmaxf(var, 0.f) + 1e-12f);
  b16x2 o;
  o[0] = (__bf16)((v0 - mean) * rstd * g[2 * t] + bt[2 * t]);
  o[1] = (__bf16)((v1 - mean) * rstd * g[2 * t + 1] + bt[2 * t + 1]);
  *(b16x2*)(ob + base + 2 * t) = o;
}

// ---------------- bf16+bf16 residual LayerNorm ----------------
__global__ __launch_bounds__(256) void ln2_bb(const __bf16* __restrict__ pre,
                                              const __bf16* __restrict__ res,
                                              const float* __restrict__ g,
                                              const float* __restrict__ bt,
                                              __bf16* __restrict__ ob) {
  int row = blockIdx.x, t = threadIdx.x;
  size_t base = (size_t)row * 512;
  b16x2 p2 = *(const b16x2*)(pre + base + 2 * t);
  b16x2 r2 = *(const b16x2*)(res + base + 2 * t);
  float v0 = (float)p2[0] + (float)r2[0];
  float v1 = (float)p2[1] + (float)r2[1];
  float s = v0 + v1, q = v0 * v0 + v1 * v1;
#pragma unroll
  for (int off = 32; off; off >>= 1) { s += __shfl_xor(s, off); q += __shfl_xor(q, off); }
  __shared__ float ls[4], lq[4];
  int wid = t >> 6, lane = t & 63;
  if (lane == 0) { ls[wid] = s; lq[wid] = q; }
  __syncthreads();
  s = ls[0] + ls[1] + ls[2] + ls[3];
  q = lq[0] + lq[1] + lq[2] + lq[3];
  float mean = s * (1.f / 512.f);
  float var = q * (1.f / 512.f) - mean * mean;
  float rstd = rsqrtf(fmaxf(var, 0.f) + 1e-12f);
  b16x2 o;
  o[0] = (__bf16)((v0 - mean) * rstd * g[2 * t] + bt[2 * t]);
  o[1] = (__bf16)((v1 - mean) * rstd * g[2 * t + 1] + bt[2 * t + 1]);
  *(b16x2*)(ob + base + 2 * t) = o;
}

// ---------------- fused masked attention; P overlays Ks; V prefetch ----------------
template<int BR>
__global__ __launch_bounds__(256, 4) void attn_branch(const __bf16* __restrict__ q,
                                                      const __bf16* __restrict__ kk_,
                                                      const __bf16* __restrict__ vt,
                                                      __bf16* __restrict__ ctx,
                                                      const int* __restrict__ lengths,
                                                      const int* __restrict__ speakers,
                                                      int sqk, int so) {
  __shared__ __attribute__((aligned(16))) __bf16 Ks[256 * 64];
  __shared__ float redM[2][32];
  __shared__ float redS[2][32];
  __shared__ float rowinv[32];
  __shared__ int spk[256];
  const int tid = threadIdx.x, lane = tid & 63, wid = tid >> 6;
  const int l15 = lane & 15, l16 = lane >> 4;
  const int bh = blockIdx.x, q0 = blockIdx.y * 32;
  const int b = bh >> 3, h = bh & 7;
  const int wq = wid & 1, wk = wid >> 1;
  const int mh = wid & 1, nh = wid >> 1;
  const __bf16* vb2 = vt + (size_t)(h * DH_) * M_ + b * T_;

  {
    const size_t kb0 = (size_t)(b * T_) * sqk + h * DH_;
    const int rsub = lane >> 3, slot = lane & 7;
#pragma unroll
    for (int j = 0; j < 8; ++j) {
      int row = (j * 4 + wid) * 8 + rsub;
      gload16(kk_ + kb0 + (size_t)row * sqk + ((slot ^ (row & 7)) * 8),
              (char*)Ks + (j * 4 + wid) * 1024);
    }
  }
  spk[tid] = speakers[b * T_ + tid];
  b16x8 af0, af1;
  {
    const __bf16* qr = q + (size_t)(b * T_ + q0 + wq * 16 + l15) * sqk + h * DH_;
    af0 = *(const b16x8*)(qr + l16 * 8);
    af1 = *(const b16x8*)(qr + 32 + l16 * 8);
  }
  __syncthreads();

  f32x4 sa[4][2] = {};
#pragma unroll
  for (int kc = 0; kc < 4; ++kc) {
#pragma unroll
    for (int nn = 0; nn < 2; ++nn) {
      int krw = kc * 64 + wk * 32 + nn * 16 + l15;
      b16x8 b0 = *(const b16x8*)((char*)Ks + krw * 128 + ((l16 ^ (krw & 7)) * 16));
      sa[kc][nn] = __builtin_amdgcn_mfma_f32_16x16x32_bf16(af0, b0, sa[kc][nn], 0, 0, 0);
      b16x8 b1 = *(const b16x8*)((char*)Ks + krw * 128 + (((4 + l16) ^ (krw & 7)) * 16));
      sa[kc][nn] = __builtin_amdgcn_mfma_f32_16x16x32_bf16(af1, b1, sa[kc][nn], 0, 0, 0);
    }
  }

  b16x8 vpre[2][2];
#pragma unroll
  for (int kt = 0; kt < 2; ++kt)
#pragma unroll
    for (int n = 0; n < 2; ++n) {
      int d = nh * 32 + n * 16 + l15;
      vpre[kt][n] = *(const b16x8*)(vb2 + (size_t)d * M_ + kt * 32 + l16 * 8);
    }

  const int L = lengths[b];
  const int rloc = wq * 16 + l16 * 4;
  float ev[4][8];
  float mx[4];
#pragma unroll
  for (int rr = 0; rr < 4; ++rr) {
    const int j = q0 + rloc + rr;
    const int spj = spk[j];
    const bool rv = j < L;
    mx[rr] = -3.4e38f;
#pragma unroll
    for (int kc = 0; kc < 4; ++kc)
#pragma unroll
      for (int nn = 0; nn < 2; ++nn) {
        int c = kc * 64 + wk * 32 + nn * 16 + l15;
        int dj = j - c;
        bool ok;
        if (BR == 0)      ok = (c < L);
        else if (BR == 1) ok = rv && (c < L) && (dj <= 2) && (dj >= -2);
        else if (BR == 2) ok = rv && (spk[c] == spj);
        else              ok = rv && (spk[c] != spj) && (c < L);
        float s = sa[kc][nn][rr] * 0.125f + (ok ? 0.0f : -10000.0f);
        ev[rr][kc * 2 + nn] = s;
        mx[rr] = fmaxf(mx[rr], s);
      }
    mx[rr] = fmaxf(mx[rr], __shfl_xor(mx[rr], 1));
    mx[rr] = fmaxf(mx[rr], __shfl_xor(mx[rr], 2));
    mx[rr] = fmaxf(mx[rr], __shfl_xor(mx[rr], 4));
    mx[rr] = fmaxf(mx[rr], __shfl_xor(mx[rr], 8));
  }
  if (l15 == 0) {
#pragma unroll
    for (int rr = 0; rr < 4; ++rr) redM[wk][rloc + rr] = mx[rr];
  }
  __syncthreads();
  float sm[4];
#pragma unroll
  for (int rr = 0; rr < 4; ++rr) {
    float mxf = fmaxf(redM[0][rloc + rr], redM[1][rloc + rr]);
    float s = 0.f;
#pragma unroll
    for (int i = 0; i < 8; ++i) { float e = __expf(ev[rr][i] - mxf); ev[rr][i] = e; s += e; }
    s += __shfl_xor(s, 1); s += __shfl_xor(s, 2); s += __shfl_xor(s, 4); s += __shfl_xor(s, 8);
    sm[rr] = s;
  }
  if (l15 == 0) {
#pragma unroll
    for (int rr = 0; rr < 4; ++rr) redS[wk][rloc + rr] = sm[rr];
  }
  __syncthreads();
  __bf16* P = (__bf16*)Ks;
#pragma unroll
  for (int rr = 0; rr < 4; ++rr) {
    if (wk == 0 && l15 == 0)
      rowinv[rloc + rr] = 1.0f / (redS[0][rloc + rr] + redS[1][rloc + rr]);
#pragma unroll
    for (int kc = 0; kc < 4; ++kc)
#pragma unroll
      for (int nn = 0; nn < 2; ++nn)
        P[(rloc + rr) * 260 + kc * 64 + wk * 32 + nn * 16 + l15] = (__bf16)ev[rr][kc * 2 + nn];
  }
  __syncthreads();

  f32x4 oa[2] = {};
#pragma unroll
  for (int kt = 0; kt < 8; ++kt) {
    b16x8 afp = *(const b16x8*)(P + (mh * 16 + l15) * 260 + kt * 32 + l16 * 8);
#pragma unroll
    for (int n = 0; n < 2; ++n) {
      b16x8 bfr;
      if (kt < 2) bfr = vpre[kt][n];
      else {
        int d = nh * 32 + n * 16 + l15;
        bfr = *(const b16x8*)(vb2 + (size_t)d * M_ + kt * 32 + l16 * 8);
      }
      oa[n] = __builtin_amdgcn_mfma_f32_16x16x32_bf16(afp, bfr, oa[n], 0, 0, 0);
    }
  }
#pragma unroll
  for (int n = 0; n < 2; ++n)
#pragma unroll
    for (int rr = 0; rr < 4; ++rr) {
      int row = mh * 16 + l16 * 4 + rr;
      ctx[(size_t)(b * T_ + q0 + row) * so + h * DH_ + nh * 32 + n * 16 + l15]
          = (__bf16)(oa[n][rr] * rowinv[row]);
    }
}

// ============================================================================
extern "C" void kernel_launch(void* const* d_in, const int* in_sizes, int n_in,
                              void* d_out, int out_size, void* d_ws, size_t ws_size,
                              hipStream_t stream) {
  const float* x        = (const float*)d_in[0];
  const int*   lengths  = (const int*)d_in[1];
  const int*   speakers = (const int*)d_in[2];
  const float* emo      = (const float*)d_in[3];
  const float* t_Wq = (const float*)d_in[4];
  const float* t_bq = (const float*)d_in[5];
  const float* t_Wk = (const float*)d_in[6];
  const float* t_bk = (const float*)d_in[7];
  const float* t_Wv = (const float*)d_in[8];
  const float* t_bv = (const float*)d_in[9];
  const float* t_Wo = (const float*)d_in[10];
  const float* t_bo = (const float*)d_in[11];
  const float* t_ln_g = (const float*)d_in[12];
  const float* t_ln_b = (const float*)d_in[13];
  const float* b_Wq = (const float*)d_in[14];
  const float* b_bq = (const float*)d_in[15];
  const float* b_Wk = (const float*)d_in[16];
  const float* b_bk = (const float*)d_in[17];
  const float* b_Wv = (const float*)d_in[18];
  const float* b_bv = (const float*)d_in[19];
  const float* b_Wo = (const float*)d_in[20];
  const float* b_bo = (const float*)d_in[21];
  const float* W1   = (const float*)d_in[22];
  const float* b1   = (const float*)d_in[23];
  const float* ln2_g = (const float*)d_in[24];
  const float* ln2_b = (const float*)d_in[25];
  const float* W2   = (const float*)d_in[26];

  if (ws_size < 232314880) return;

  char* ws = (char*)d_ws;
  // wT slots: 0=W2t  [2+2i,3+2i]=WqT_i/WkT_i  [10+i]=WvT_i  14..17=W1t
  __bf16* wT      = (__bf16*)(ws);
  __bf16* bWo_bf  = (__bf16*)(ws + 9437184);
  __bf16* Btbig   = (__bf16*)(ws + 11534336);
  float*  qkbias  = (float*)(ws + 13631488);
  float*  bias2   = (float*)(ws + 13647872);
  float*  kemo    = (float*)(ws + 13649920);
  float*  vemo    = (float*)(ws + 13664256);
  __bf16* Wqk_bf  = (__bf16*)(ws + 13678592);
  __bf16* VWo_bf  = (__bf16*)(ws + 13744128);
  float*  sbias   = (float*)(ws + 13809664);
  __bf16* xb      = (__bf16*)(ws + 13908224);
  __bf16* htb     = (__bf16*)(ws + 30685440);
  __bf16* qkb     = (__bf16*)(ws + 47462656);
  __bf16* vtb_all = (__bf16*)(ws + 81017088);
  __bf16* ctxa    = (__bf16*)(ws + 148125952);
  __bf16* heb  = xb;
  __bf16* tmpb = qkb;
  float*  partial = (float*)qkb;
  float*  scores  = (float*)qkb;
  __bf16* Pmat    = (__bf16*)(ws + 47462656 + 4194304);
  __bf16* sctx    = (__bf16*)(ws + 47462656 + 8388608);

  // conversions + transposes
  cvt_f32_bf16_k<<<dim3(8192), 256, 0, stream>>>(x, xb);
  cvt_f32_bf16_k<<<dim3(1024), 256, 0, stream>>>(b_Wo, bWo_bf);
  {
    TP15 p;
    const float* srcs[13] = {b_Wq, b_Wq + SL, b_Wq + 2 * SL, b_Wq + 3 * SL,
                             b_Wk, b_Wk + SL, b_Wk + 2 * SL, b_Wk + 3 * SL,
                             b_Wv, b_Wv + SL, b_Wv + 2 * SL, b_Wv + 3 * SL,
                             W2};
    const int slots[13] = {2, 4, 6, 8, 3, 5, 7, 9, 10, 11, 12, 13, 0};
    for (int i = 0; i < 13; ++i) { p.src[i] = srcs[i]; p.slot[i] = slots[i]; }
    for (int i = 13; i < 15; ++i) { p.src[i] = W2; p.slot[i] = 0; }
    transpose_cvt15<<<dim3(16, 16, 13), 256, 0, stream>>>(p, wT);
  }
  transpose_cvt<<<dim3(16, 64), 256, 0, stream>>>(W1, wT + 14 * SL, 2048, 512);
  emo_kv<<<dim3(7, 2), 512, 0, stream>>>(emo, t_Wk, t_bk, t_Wv, t_bv, kemo, vemo);
  concat_qk_bias<<<dim3(4), 512, 0, stream>>>(b_bq, b_bk, qkbias);
  bias2_p1<<<dim3(16), 256, 0, stream>>>(b_bo, W1, partial);
  bias2_p2<<<dim3(2), 256, 0, stream>>>(b1, partial, bias2);
  sentprep<<<dim3(56), 512, 0, stream>>>(t_Wq, t_bq, t_Wo, kemo, vemo, Wqk_bf, VWo_bf, sbias);
  sentpad<<<dim3(8), 512, 0, stream>>>(Wqk_bf, sbias);
  // Btbig[o][i*512+n] = (Wo_i . W1_i)^T, batched over i via z
  gemm_bt64<true, 0, 0><<<dim3(8, 4, 4), 256, 0, stream>>>(wT + 14 * SL, bWo_bf, nullptr, Btbig,
                                                           512, 512, 2048, 2048, 512, SL, 512);

  // sentiment block on MFMA: scores -> softmax -> P@VWo -> LN
  gemm_bt64<false, 1, 0><<<dim3(1, 128), 256, 0, stream>>>(xb, Wqk_bf, sbias, scores,
                                                           64, 512, 512, 64, 0, 0, 0);
  softmax7<<<dim3(512), 256, 0, stream>>>(scores, Pmat);
  gemm_bt64<true, 1, 0><<<dim3(8, 128), 256, 0, stream>>>(Pmat, VWo_bf, t_bo, sctx,
                                                          512, 64, 64, 512, 0, 0, 0);
  ln1_bf<<<dim3(16384), 256, 0, stream>>>(sctx, x, t_ln_g, t_ln_b, htb);

  // merged V^T for all 4 branches: [2048][16384] = WvT_all @ htb^T + bv
  // col-chunk swizzle: each XCD owns 32 bx (2048 tokens) -> htb panel 2MB L2-resident
  gemm_bt64<true, 2, 1><<<dim3(256, 16), 256, 0, stream>>>(wT + 10 * SL, htb, b_bv,
                                                           vtb_all, 16384, 512, 512, 16384, 0, 0, 0);

  // four masked attention branches (qk proj on the 128x64 tile, 2048 blocks)
  for (int i = 0; i < 4; ++i) {
    gemm_bt64<true, 1, 0><<<dim3(16, 128), 256, 0, stream>>>(htb, wT + (2 + 2 * i) * SL, qkbias + i * 1024,
                                                             qkb, 1024, 512, 512, 1024, 0, 0, 0);
    dim3 ag(512, 8);
    const __bf16* vti = vtb_all + (size_t)i * 512 * M_;
    switch (i) {
      case 0: attn_branch<0><<<ag, 256, 0, stream>>>(qkb, qkb + 512, vti, ctxa + 0 * 512, lengths, speakers, 1024, 2048); break;
      case 1: attn_branch<1><<<ag, 256, 0, stream>>>(qkb, qkb + 512, vti, ctxa + 1 * 512, lengths, speakers, 1024, 2048); break;
      case 2: attn_branch<2><<<ag, 256, 0, stream>>>(qkb, qkb + 512, vti, ctxa + 2 * 512, lengths, speakers, 1024, 2048); break;
      case 3: attn_branch<3><<<ag, 256, 0, stream>>>(qkb, qkb + 512, vti, ctxa + 3 * 512, lengths, speakers, 1024, 2048); break;
    }
  }

  // fused (cat @ blockdiag(Wo) @ W1): one K=2048 GEMM -> bf16
  gemm_bt64<true, 1, 0><<<dim3(8, 128), 256, 0, stream>>>(ctxa, Btbig, bias2, tmpb, 512, 2048, 2048, 512, 0, 0, 0);
  ln2_bb<<<dim3(16384), 256, 0, stream>>>(tmpb, htb, ln2_g, ln2_b, heb);
  gemm_bt64<false, 0, 0><<<dim3(8, 128), 256, 0, stream>>>(heb, wT + 0 * SL, nullptr, (float*)d_out, 512, 512, 512, 512, 0, 0, 0);
}